// Round 2
// baseline (5981.907 us; speedup 1.0000x reference)
//
#include <hip/hip_runtime.h>

#define DD 64
#define HH 256
#define WW 256
#define HW (HH * WW)      // 65536
#define NVOX (DD * HW)    // 4194304

#define TS 32             // output tile (H and W)
#define DR 36             // deriv region = TS+4
#define HR 34             // hidden region = TS+2
#define HPAD 36           // hbuf row stride (even -> float2-aligned windows)

// ---------------------------------------------------------------------------
// Kernel A: corr[h,w] = (sino[h,w] - sum_d t[d,h,w]) / DD
// ---------------------------------------------------------------------------
__global__ __launch_bounds__(256) void k_corr(const float* __restrict__ t,
                                              const float* __restrict__ sino,
                                              float* __restrict__ corr) {
  int idx = blockIdx.x * 256 + threadIdx.x;  // 0..HW-1
  float s = 0.f;
#pragma unroll 8
  for (int d = 0; d < DD; ++d) s += t[d * HW + idx];
  corr[idx] = (sino[idx] - s) * (1.0f / DD);
}

// ---------------------------------------------------------------------------
// Kernel B: fused BasicBlock(b) on input deriv_b(z), z = t + corr broadcast.
//   b=0: d/dx (W), b=1: d/dy (H), b=2: d/dz (D), b=3: identity.
// Depth sweep with ring-buffered deriv planes (dbuf) and hidden planes (hbuf).
// ---------------------------------------------------------------------------
__global__ __launch_bounds__(256, 1) void k_blocks(
    const float* __restrict__ t, const float* __restrict__ corr,
    float* __restrict__ p, float* __restrict__ q, float* __restrict__ s_,
    float* __restrict__ zb,
    const float* __restrict__ W1g, const float* __restrict__ B1g,
    const float* __restrict__ W2g, const float* __restrict__ B2g,
    const float* __restrict__ ntx, const float* __restrict__ nty,
    const float* __restrict__ ntz, const float* __restrict__ nt, int c) {
  __shared__ float dbuf[3][DR][DR];                    // 15.6 KB
  __shared__ __align__(16) float hbuf[3][8][HR][HPAD]; // 117.5 KB

  const int b = blockIdx.z;
  const int ty0 = blockIdx.y * TS;
  const int tx0 = blockIdx.x * TS;
  const int tid = threadIdx.x;

  const float* w1 = W1g + b * 216;  // [8][3][3][3]
  const float* w2 = W2g + b * 216;  // [8][3][3][3] (W2 shape (4,1,8,3,3,3))
  float b1[8];
#pragma unroll
  for (int ch = 0; ch < 8; ++ch) b1[ch] = B1g[b * 8 + ch];
  const float b2 = B2g[b];
  const float coef = (b == 0) ? ntx[c] : (b == 1) ? nty[c] : (b == 2) ? ntz[c] : nt[c];
  const float* prevBuf = (b == 0) ? p : (b == 1) ? q : (b == 2) ? s_ : t;
  float* outBuf = (b == 0) ? p : (b == 1) ? q : (b == 2) ? s_ : zb;
  const bool zeroPrev = (c == 0) && (b < 3);

  // ---- deriv plane f -> dbuf[sl] over region [ty0-2,ty0+34) x [tx0-2,tx0+34)
  auto load_deriv = [&](int f, int sl) {
    for (int i = tid; i < DR * DR; i += 256) {
      int iy = i / DR, ix = i - iy * DR;
      int gy = ty0 - 2 + iy, gx = tx0 - 2 + ix;
      float v = 0.f;
      if (f >= 0 && f < DD && gy >= 0 && gy < HH && gx >= 0 && gx < WW) {
        int base = f * HW + gy * WW + gx;
        int cb = gy * WW + gx;
        if (b == 0) {
          if (gx + 1 < WW) v = t[base + 1] - t[base] + corr[cb + 1] - corr[cb];
        } else if (b == 1) {
          if (gy + 1 < HH) v = t[base + WW] - t[base] + corr[cb + WW] - corr[cb];
        } else if (b == 2) {
          if (f + 1 < DD) v = t[base + HW] - t[base];  // corr cancels along D
        } else {
          v = t[base] + corr[cb];
        }
      }
      dbuf[sl][iy][ix] = v;
    }
  };

  // ---- hidden plane e -> hbuf[e%3]; reads dbuf planes e-1,e,e+1
  // NOTE: hidden exists only INSIDE the volume; conv2's SAME padding
  // zero-pads it. Out-of-volume (gy/gx == -1 or 256) positions MUST be 0,
  // not relu(conv of the partially-overlapping deriv halo).  [R1 fix]
  auto comp_hidden = [&](int e) {
    int se = e % 3;
    if (e >= DD) {  // conv zero-pad plane along D
      for (int i = tid; i < 8 * HR * HPAD; i += 256) (&hbuf[se][0][0][0])[i] = 0.f;
      return;
    }
    int sd[3] = {(e + 2) % 3, e % 3, (e + 1) % 3};
    for (int i = tid; i < HR * HR; i += 256) {
      int jy = i / HR, jx = i - jy * HR;
      int gy = ty0 - 1 + jy, gx = tx0 - 1 + jx;
      bool inside = ((unsigned)gy < HH) && ((unsigned)gx < WW);
      float dv[27];
#pragma unroll
      for (int kz = 0; kz < 3; ++kz)
#pragma unroll
        for (int ky = 0; ky < 3; ++ky)
#pragma unroll
          for (int kx = 0; kx < 3; ++kx)
            dv[kz * 9 + ky * 3 + kx] = dbuf[sd[kz]][jy + ky][jx + kx];
      float acc[8];
#pragma unroll
      for (int ch = 0; ch < 8; ++ch) acc[ch] = b1[ch];
#pragma unroll
      for (int ch = 0; ch < 8; ++ch)
#pragma unroll
        for (int tt = 0; tt < 27; ++tt)
          acc[ch] = fmaf(w1[ch * 27 + tt], dv[tt], acc[ch]);
#pragma unroll
      for (int ch = 0; ch < 8; ++ch)
        hbuf[se][ch][jy][jx] = inside ? fmaxf(acc[ch], 0.f) : 0.f;
    }
  };

  // ---- output plane d: conv2 over hidden planes d-1,d,d+1; 2x2 patch/thread
  auto comp_out = [&](int d) {
    int txi = tid & 15, tyi = tid >> 4;
    int px0 = txi * 2, py0 = tyi * 2;
    float acc[2][2] = {{b2, b2}, {b2, b2}};
#pragma unroll
    for (int kz = 0; kz < 3; ++kz) {
      int e = d - 1 + kz;
      int se = (e + 3) % 3;  // e=-1 -> slot 2 (pre-zeroed); e=64 -> zeroed slot
#pragma unroll
      for (int ch = 0; ch < 8; ++ch) {
        float hwf[4][4];
#pragma unroll
        for (int r = 0; r < 4; ++r) {
          const float2* row = (const float2*)&hbuf[se][ch][py0 + r][px0];
          float2 a = row[0], bb = row[1];
          hwf[r][0] = a.x; hwf[r][1] = a.y; hwf[r][2] = bb.x; hwf[r][3] = bb.y;
        }
#pragma unroll
        for (int ky = 0; ky < 3; ++ky)
#pragma unroll
          for (int kx = 0; kx < 3; ++kx) {
            float wv = w2[ch * 27 + kz * 9 + ky * 3 + kx];
#pragma unroll
            for (int i = 0; i < 2; ++i)
#pragma unroll
              for (int j = 0; j < 2; ++j)
                acc[i][j] = fmaf(wv, hwf[i + ky][j + kx], acc[i][j]);
          }
      }
    }
#pragma unroll
    for (int i = 0; i < 2; ++i) {
      int gy = ty0 + py0 + i, gx = tx0 + px0;
      long v = (long)d * HW + gy * WW + gx;
      float2 pr;
      if (zeroPrev) { pr.x = 0.f; pr.y = 0.f; }
      else pr = *(const float2*)&prevBuf[v];
      float2 o;
      o.x = pr.x + coef * (pr.x - acc[i][0]);
      o.y = pr.y + coef * (pr.y - acc[i][1]);
      *(float2*)&outBuf[v] = o;
    }
  };

  // ---- prologue: zero slots for plane -1, load deriv f=0,1, hidden e=0
  for (int i = tid; i < DR * DR; i += 256) (&dbuf[2][0][0])[i] = 0.f;
  for (int i = tid; i < 8 * HR * HPAD; i += 256) (&hbuf[2][0][0][0])[i] = 0.f;
  load_deriv(0, 0);
  load_deriv(1, 1);
  __syncthreads();
  comp_hidden(0);
  __syncthreads();

  for (int d = 0; d < DD; ++d) {
    load_deriv(d + 2, (d + 2) % 3);  // f>=DD handled as zeros
    __syncthreads();
    comp_hidden(d + 1);              // e=DD -> zero slot
    __syncthreads();
    comp_out(d);
    // WAR on hbuf slot read by comp_out is fenced by the sync after load_deriv
  }
}

// ---------------------------------------------------------------------------
// Kernel C: t_next = fdiff_t(p,x) + fdiff_t(q,y) + fdiff_t(s,z) + zb
// ---------------------------------------------------------------------------
__global__ __launch_bounds__(256) void k_combine(
    const float* __restrict__ p, const float* __restrict__ q,
    const float* __restrict__ s_, const float* __restrict__ zb,
    float* __restrict__ tn) {
  int idx = blockIdx.x * 256 + threadIdx.x;
  int x = idx & (WW - 1);
  int y = (idx >> 8) & (HH - 1);
  int d = idx >> 16;
  float v = zb[idx];
  v += (x > 0 ? p[idx - 1] : 0.f) - (x < WW - 1 ? p[idx] : 0.f);
  v += (y > 0 ? q[idx - WW] : 0.f) - (y < HH - 1 ? q[idx] : 0.f);
  v += (d > 0 ? s_[idx - HW] : 0.f) - (d < DD - 1 ? s_[idx] : 0.f);
  tn[idx] = v;
}

// ---------------------------------------------------------------------------
extern "C" void kernel_launch(void* const* d_in, const int* in_sizes, int n_in,
                              void* d_out, int out_size, void* d_ws, size_t ws_size,
                              hipStream_t stream) {
  const float* image = (const float*)d_in[0];
  const float* sino  = (const float*)d_in[1];
  const float* W1    = (const float*)d_in[2];
  const float* B1    = (const float*)d_in[3];
  const float* W2    = (const float*)d_in[4];
  const float* B2    = (const float*)d_in[5];
  const float* ntx   = (const float*)d_in[6];
  const float* nty   = (const float*)d_in[7];
  const float* ntz   = (const float*)d_in[8];
  const float* nt    = (const float*)d_in[9];
  float* out = (float*)d_out;

  // workspace layout: corr(HW) | p | q | s | zb  -> 67.4 MB total
  float* corr = (float*)d_ws;
  float* p  = corr + HW;
  float* q  = p + NVOX;
  float* s_ = q + NVOX;
  float* zb = s_ + NVOX;

  // outs[0] = image
  hipMemcpyAsync(out, image, (size_t)NVOX * sizeof(float),
                 hipMemcpyDeviceToDevice, stream);

  for (int c = 0; c < 3; ++c) {
    const float* t = out + (size_t)c * NVOX;
    float* tn = out + (size_t)(c + 1) * NVOX;
    k_corr<<<HW / 256, 256, 0, stream>>>(t, sino, corr);
    k_blocks<<<dim3(WW / TS, HH / TS, 4), 256, 0, stream>>>(
        t, corr, p, q, s_, zb, W1, B1, W2, B2, ntx, nty, ntz, nt, c);
    k_combine<<<NVOX / 256, 256, 0, stream>>>(p, q, s_, zb, tn);
  }
}

// Round 3
// 2404.873 us; speedup vs baseline: 2.4874x; 2.4874x over previous
//
#include <hip/hip_runtime.h>

#define DD 64
#define HH 256
#define WW 256
#define HW (HH * WW)      // 65536
#define NVOX (DD * HW)    // 4194304

#define TS 32             // output tile (H and W)
#define DR 36             // deriv region = TS+4
#define HR 34             // hidden region = TS+2
#define HPAD 36           // hbuf row stride (even -> float2-aligned windows)

// ---------------------------------------------------------------------------
// Kernel A: corr[h,w] = (sino[h,w] - sum_d t[d,h,w]) / DD
// ---------------------------------------------------------------------------
__global__ __launch_bounds__(256) void k_corr(const float* __restrict__ t,
                                              const float* __restrict__ sino,
                                              float* __restrict__ corr) {
  int idx = blockIdx.x * 256 + threadIdx.x;  // 0..HW-1
  float s = 0.f;
#pragma unroll 8
  for (int d = 0; d < DD; ++d) s += t[d * HW + idx];
  corr[idx] = (sino[idx] - s) * (1.0f / DD);
}

// ---------------------------------------------------------------------------
// Kernel B: fused BasicBlock(b) on input deriv_b(z), z = t + corr broadcast.
//   b=0: d/dx (W), b=1: d/dy (H), b=2: d/dz (D), b=3: identity.
// Depth sweep with ring-buffered deriv planes (dbuf) and hidden planes (hbuf).
// R2: unroll discipline — ch loops are `#pragma unroll 1` so the live set
// stays ~60 VGPRs (R1 fully unrolled kz*ch*hwf -> >256 live -> scratch spill,
// 850 MB/dispatch write traffic, 12.7x amplification).
// ---------------------------------------------------------------------------
__global__ __launch_bounds__(256, 1) void k_blocks(
    const float* __restrict__ t, const float* __restrict__ corr,
    float* __restrict__ p, float* __restrict__ q, float* __restrict__ s_,
    float* __restrict__ zb,
    const float* __restrict__ W1g, const float* __restrict__ B1g,
    const float* __restrict__ W2g, const float* __restrict__ B2g,
    const float* __restrict__ ntx, const float* __restrict__ nty,
    const float* __restrict__ ntz, const float* __restrict__ nt, int c) {
  __shared__ float dbuf[3][DR][DR];                    // 15.6 KB
  __shared__ __align__(16) float hbuf[3][8][HR][HPAD]; // 117.5 KB

  const int b = blockIdx.z;
  const int ty0 = blockIdx.y * TS;
  const int tx0 = blockIdx.x * TS;
  const int tid = threadIdx.x;

  const float* w1 = W1g + b * 216;  // [8][3][3][3]
  const float* w2 = W2g + b * 216;  // [8][3][3][3] (W2 shape (4,1,8,3,3,3))
  const float b2 = B2g[b];
  const float coef = (b == 0) ? ntx[c] : (b == 1) ? nty[c] : (b == 2) ? ntz[c] : nt[c];
  const float* prevBuf = (b == 0) ? p : (b == 1) ? q : (b == 2) ? s_ : t;
  float* outBuf = (b == 0) ? p : (b == 1) ? q : (b == 2) ? s_ : zb;
  const bool zeroPrev = (c == 0) && (b < 3);

  // ---- deriv plane f -> dbuf[sl] over region [ty0-2,ty0+34) x [tx0-2,tx0+34)
  auto load_deriv = [&](int f, int sl) {
    for (int i = tid; i < DR * DR; i += 256) {
      int iy = i / DR, ix = i - iy * DR;
      int gy = ty0 - 2 + iy, gx = tx0 - 2 + ix;
      float v = 0.f;
      if (f >= 0 && f < DD && (unsigned)gy < HH && (unsigned)gx < WW) {
        int base = f * HW + gy * WW + gx;
        int cb = gy * WW + gx;
        if (b == 0) {
          if (gx + 1 < WW) v = t[base + 1] - t[base] + corr[cb + 1] - corr[cb];
        } else if (b == 1) {
          if (gy + 1 < HH) v = t[base + WW] - t[base] + corr[cb + WW] - corr[cb];
        } else if (b == 2) {
          if (f + 1 < DD) v = t[base + HW] - t[base];  // corr cancels along D
        } else {
          v = t[base] + corr[cb];
        }
      }
      dbuf[sl][iy][ix] = v;
    }
  };

  // ---- hidden plane e -> hbuf[e%3]; reads dbuf planes e-1,e,e+1
  // Hidden exists only INSIDE the volume; conv2's SAME padding zero-pads it.
  auto comp_hidden = [&](int e) {
    int se = e % 3;
    if (e >= DD) {  // conv zero-pad plane along D
      for (int i = tid; i < 8 * HR * HPAD; i += 256) (&hbuf[se][0][0][0])[i] = 0.f;
      return;
    }
    int s0 = (e + 2) % 3, s1 = e % 3, s2 = (e + 1) % 3;
    for (int i = tid; i < HR * HR; i += 256) {
      int jy = i / HR, jx = i - jy * HR;
      int gy = ty0 - 1 + jy, gx = tx0 - 1 + jx;
      bool inside = ((unsigned)gy < HH) && ((unsigned)gx < WW);
      float dv[27];
#pragma unroll
      for (int ky = 0; ky < 3; ++ky)
#pragma unroll
        for (int kx = 0; kx < 3; ++kx) {
          dv[0 * 9 + ky * 3 + kx] = dbuf[s0][jy + ky][jx + kx];
          dv[1 * 9 + ky * 3 + kx] = dbuf[s1][jy + ky][jx + kx];
          dv[2 * 9 + ky * 3 + kx] = dbuf[s2][jy + ky][jx + kx];
        }
#pragma unroll 1
      for (int ch = 0; ch < 8; ++ch) {  // unroll 1: cap live set (R2 fix)
        float a = B1g[b * 8 + ch];
#pragma unroll
        for (int tt = 0; tt < 27; ++tt)
          a = fmaf(w1[ch * 27 + tt], dv[tt], a);
        hbuf[se][ch][jy][jx] = inside ? fmaxf(a, 0.f) : 0.f;
      }
    }
  };

  // ---- output plane d: conv2 over hidden planes d-1,d,d+1; 2x2 patch/thread
  auto comp_out = [&](int d) {
    int txi = tid & 15, tyi = tid >> 4;
    int px0 = txi * 2, py0 = tyi * 2;
    float acc[2][2] = {{b2, b2}, {b2, b2}};
#pragma unroll 1
    for (int ch = 0; ch < 8; ++ch) {  // unroll 1: cap live set (R2 fix)
#pragma unroll
      for (int kz = 0; kz < 3; ++kz) {
        int se = (d + 2 + kz) % 3;  // e=d-1+kz; e=-1 -> slot 2 (pre-zeroed)
        float hwf[4][4];
#pragma unroll
        for (int r = 0; r < 4; ++r) {
          const float2* row = (const float2*)&hbuf[se][ch][py0 + r][px0];
          float2 a = row[0], bb = row[1];
          hwf[r][0] = a.x; hwf[r][1] = a.y; hwf[r][2] = bb.x; hwf[r][3] = bb.y;
        }
#pragma unroll
        for (int ky = 0; ky < 3; ++ky)
#pragma unroll
          for (int kx = 0; kx < 3; ++kx) {
            float wv = w2[ch * 27 + kz * 9 + ky * 3 + kx];
#pragma unroll
            for (int i = 0; i < 2; ++i)
#pragma unroll
              for (int j = 0; j < 2; ++j)
                acc[i][j] = fmaf(wv, hwf[i + ky][j + kx], acc[i][j]);
          }
      }
    }
#pragma unroll
    for (int i = 0; i < 2; ++i) {
      int gy = ty0 + py0 + i, gx = tx0 + px0;
      long v = (long)d * HW + gy * WW + gx;
      float2 pr;
      if (zeroPrev) { pr.x = 0.f; pr.y = 0.f; }
      else pr = *(const float2*)&prevBuf[v];
      float2 o;
      o.x = pr.x + coef * (pr.x - acc[i][0]);
      o.y = pr.y + coef * (pr.y - acc[i][1]);
      *(float2*)&outBuf[v] = o;
    }
  };

  // ---- prologue: zero slots for plane -1, load deriv f=0,1, hidden e=0
  for (int i = tid; i < DR * DR; i += 256) (&dbuf[2][0][0])[i] = 0.f;
  for (int i = tid; i < 8 * HR * HPAD; i += 256) (&hbuf[2][0][0][0])[i] = 0.f;
  load_deriv(0, 0);
  load_deriv(1, 1);
  __syncthreads();
  comp_hidden(0);
  __syncthreads();

  for (int d = 0; d < DD; ++d) {
    load_deriv(d + 2, (d + 2) % 3);  // f>=DD handled as zeros
    __syncthreads();
    comp_hidden(d + 1);              // e=DD -> zero slot
    __syncthreads();
    comp_out(d);
    // WAR on hbuf slot read by comp_out is fenced by the sync after load_deriv
  }
}

// ---------------------------------------------------------------------------
// Kernel C: t_next = fdiff_t(p,x) + fdiff_t(q,y) + fdiff_t(s,z) + zb
// ---------------------------------------------------------------------------
__global__ __launch_bounds__(256) void k_combine(
    const float* __restrict__ p, const float* __restrict__ q,
    const float* __restrict__ s_, const float* __restrict__ zb,
    float* __restrict__ tn) {
  int idx = blockIdx.x * 256 + threadIdx.x;
  int x = idx & (WW - 1);
  int y = (idx >> 8) & (HH - 1);
  int d = idx >> 16;
  float v = zb[idx];
  v += (x > 0 ? p[idx - 1] : 0.f) - (x < WW - 1 ? p[idx] : 0.f);
  v += (y > 0 ? q[idx - WW] : 0.f) - (y < HH - 1 ? q[idx] : 0.f);
  v += (d > 0 ? s_[idx - HW] : 0.f) - (d < DD - 1 ? s_[idx] : 0.f);
  tn[idx] = v;
}

// ---------------------------------------------------------------------------
extern "C" void kernel_launch(void* const* d_in, const int* in_sizes, int n_in,
                              void* d_out, int out_size, void* d_ws, size_t ws_size,
                              hipStream_t stream) {
  const float* image = (const float*)d_in[0];
  const float* sino  = (const float*)d_in[1];
  const float* W1    = (const float*)d_in[2];
  const float* B1    = (const float*)d_in[3];
  const float* W2    = (const float*)d_in[4];
  const float* B2    = (const float*)d_in[5];
  const float* ntx   = (const float*)d_in[6];
  const float* nty   = (const float*)d_in[7];
  const float* ntz   = (const float*)d_in[8];
  const float* nt    = (const float*)d_in[9];
  float* out = (float*)d_out;

  // workspace layout: corr(HW) | p | q | s | zb  -> 67.4 MB total
  float* corr = (float*)d_ws;
  float* p  = corr + HW;
  float* q  = p + NVOX;
  float* s_ = q + NVOX;
  float* zb = s_ + NVOX;

  // outs[0] = image
  hipMemcpyAsync(out, image, (size_t)NVOX * sizeof(float),
                 hipMemcpyDeviceToDevice, stream);

  for (int c = 0; c < 3; ++c) {
    const float* t = out + (size_t)c * NVOX;
    float* tn = out + (size_t)(c + 1) * NVOX;
    k_corr<<<HW / 256, 256, 0, stream>>>(t, sino, corr);
    k_blocks<<<dim3(WW / TS, HH / TS, 4), 256, 0, stream>>>(
        t, corr, p, q, s_, zb, W1, B1, W2, B2, ntx, nty, ntz, nt, c);
    k_combine<<<NVOX / 256, 256, 0, stream>>>(p, q, s_, zb, tn);
  }
}

// Round 4
// 1377.498 us; speedup vs baseline: 4.3426x; 1.7458x over previous
//
#include <hip/hip_runtime.h>

#define DD 64
#define HH 256
#define WW 256
#define HW (HH * WW)      // 65536
#define NVOX (DD * HW)    // 4194304

#define TS 32             // output tile (H and W)
#define DR 36             // deriv region = TS+4
#define HR 34             // hidden region = TS+2
#define HP 36             // hbuf row stride (even -> float2-aligned windows)
#define CH 32             // depth chunk (DD/2): grid z = 4 blocks x 2 chunks

// ---------------------------------------------------------------------------
// Kernel A: corr[h,w] = (sino[h,w] - sum_d t[d,h,w]) / DD
// ---------------------------------------------------------------------------
__global__ __launch_bounds__(256) void k_corr(const float* __restrict__ t,
                                              const float* __restrict__ sino,
                                              float* __restrict__ corr) {
  int idx = blockIdx.x * 256 + threadIdx.x;  // 0..HW-1
  float s = 0.f;
#pragma unroll 8
  for (int d = 0; d < DD; ++d) s += t[d * HW + idx];
  corr[idx] = (sino[idx] - s) * (1.0f / DD);
}

// ---------------------------------------------------------------------------
// Kernel B (R4 restructure): fused BasicBlock(b) on deriv_b(z), z = t + corr.
//   b=0: d/dx (W), b=1: d/dy (H), b=2: d/dz (D), b=3: identity.
// One hidden plane in LDS at a time; conv2 is applied scatter-style into a
// 3-deep register ring (aM/aC/aP = planes e-1, e, e+1), rotated by name.
// 3x fewer conv2 LDS reads than R3; LDS 133->54.7 KB; depth-split x2 gives
// grid 512 = 2 WG/CU = 2 waves/SIMD (R3 was 1 wave/SIMD, latency-exposed).
// ---------------------------------------------------------------------------
__global__ __launch_bounds__(256, 2) void k_blocks(
    const float* __restrict__ t, const float* __restrict__ corr,
    float* __restrict__ p, float* __restrict__ q, float* __restrict__ s_,
    float* __restrict__ zb,
    const float* __restrict__ W1g, const float* __restrict__ B1g,
    const float* __restrict__ W2g, const float* __restrict__ B2g,
    const float* __restrict__ ntx, const float* __restrict__ nty,
    const float* __restrict__ ntz, const float* __restrict__ nt, int c) {
  __shared__ float dbuf[3][DR][DR];                 // 15.6 KB
  __shared__ __align__(16) float hbuf[8][HR][HP];   // 39.2 KB (one hidden plane)

  const int b = blockIdx.z & 3;
  const int D0 = (blockIdx.z >> 2) * CH;            // depth chunk start
  const int ty0 = blockIdx.y * TS;
  const int tx0 = blockIdx.x * TS;
  const int tid = threadIdx.x;

  const float* w1 = W1g + b * 216;  // [8][3][3][3]
  const float* w2 = W2g + b * 216;  // [8][3][3][3] (W2 shape (4,1,8,3,3,3))
  const float b2 = B2g[b];
  const float coef = (b == 0) ? ntx[c] : (b == 1) ? nty[c] : (b == 2) ? ntz[c] : nt[c];
  const float* prevBuf = (b == 0) ? p : (b == 1) ? q : (b == 2) ? s_ : t;
  float* outBuf = (b == 0) ? p : (b == 1) ? q : (b == 2) ? s_ : zb;
  const bool zeroPrev = (c == 0) && (b < 3);

  // slot for deriv plane f (f ranges D0-2 .. D0+CH+2, can be negative)
  auto dslot = [](int f) { return (f + 6) % 3; };

  // ---- deriv plane f -> dbuf[dslot(f)]; out-of-range f writes zeros
  auto load_deriv = [&](int f) {
    int sl = dslot(f);
    for (int i = tid; i < DR * DR; i += 256) {
      int iy = i / DR, ix = i - iy * DR;
      int gy = ty0 - 2 + iy, gx = tx0 - 2 + ix;
      float v = 0.f;
      if (f >= 0 && f < DD && (unsigned)gy < HH && (unsigned)gx < WW) {
        int base = f * HW + gy * WW + gx;
        int cb = gy * WW + gx;
        if (b == 0) {
          if (gx + 1 < WW) v = t[base + 1] - t[base] + corr[cb + 1] - corr[cb];
        } else if (b == 1) {
          if (gy + 1 < HH) v = t[base + WW] - t[base] + corr[cb + WW] - corr[cb];
        } else if (b == 2) {
          if (f + 1 < DD) v = t[base + HW] - t[base];  // corr cancels along D
        } else {
          v = t[base] + corr[cb];
        }
      }
      dbuf[sl][iy][ix] = v;
    }
  };

  // ---- hidden plane e (0<=e<DD) -> hbuf; reads dbuf planes e-1,e,e+1.
  // Hidden exists only INSIDE the volume; conv2 SAME zero-pads it (R1 fix).
  auto comp_hidden = [&](int e) {
    int s0 = dslot(e - 1), s1 = dslot(e), s2 = dslot(e + 1);
    for (int i = tid; i < HR * HR; i += 256) {
      int jy = i / HR, jx = i - jy * HR;
      int gy = ty0 - 1 + jy, gx = tx0 - 1 + jx;
      bool inside = ((unsigned)gy < HH) && ((unsigned)gx < WW);
      float dv[27];
#pragma unroll
      for (int ky = 0; ky < 3; ++ky)
#pragma unroll
        for (int kx = 0; kx < 3; ++kx) {
          dv[0 * 9 + ky * 3 + kx] = dbuf[s0][jy + ky][jx + kx];
          dv[1 * 9 + ky * 3 + kx] = dbuf[s1][jy + ky][jx + kx];
          dv[2 * 9 + ky * 3 + kx] = dbuf[s2][jy + ky][jx + kx];
        }
#pragma unroll 2
      for (int ch = 0; ch < 8; ++ch) {  // unroll 2: ILP without spill (R2/R4)
        float a = B1g[b * 8 + ch];
#pragma unroll
        for (int tt = 0; tt < 27; ++tt)
          a = fmaf(w1[ch * 27 + tt], dv[tt], a);
        hbuf[ch][jy][jx] = inside ? fmaxf(a, 0.f) : 0.f;
      }
    }
  };

  const int txi = tid & 15, tyi = tid >> 4;
  const int px0 = txi * 2, py0 = tyi * 2;

  // register ring: aM = plane e-1, aC = plane e, aP = plane e+1
  float aM[2][2], aC[2][2], aP[2][2];
#pragma unroll
  for (int i = 0; i < 2; ++i)
#pragma unroll
    for (int j = 0; j < 2; ++j) { aM[i][j] = b2; aC[i][j] = b2; aP[i][j] = b2; }

  // prologue: deriv planes D0-2, D0-1, D0 (out-of-range -> zeros)
  load_deriv(D0 - 2);
  load_deriv(D0 - 1);
  load_deriv(D0);
  __syncthreads();

  for (int e = D0 - 1; e <= D0 + CH; ++e) {
    const bool live = (e >= 0 && e < DD);
    if (live) comp_hidden(e);
    __syncthreads();
    if (live) {
      // scatter hidden e into aP(kz=0 -> e+1), aC(kz=1 -> e), aM(kz=2 -> e-1)
#pragma unroll 1
      for (int ch = 0; ch < 8; ++ch) {  // unroll 1: cap live set (R2 fix)
        float hwf[4][4];
#pragma unroll
        for (int r = 0; r < 4; ++r) {
          const float2* row = (const float2*)&hbuf[ch][py0 + r][px0];
          float2 a0 = row[0], a1 = row[1];
          hwf[r][0] = a0.x; hwf[r][1] = a0.y; hwf[r][2] = a1.x; hwf[r][3] = a1.y;
        }
        const float* wch = w2 + ch * 27;
#pragma unroll
        for (int ky = 0; ky < 3; ++ky)
#pragma unroll
          for (int kx = 0; kx < 3; ++kx) {
            float w0 = wch[0 + ky * 3 + kx];
            float w1v = wch[9 + ky * 3 + kx];
            float w2v = wch[18 + ky * 3 + kx];
#pragma unroll
            for (int i = 0; i < 2; ++i)
#pragma unroll
              for (int j = 0; j < 2; ++j) {
                float h = hwf[i + ky][j + kx];
                aP[i][j] = fmaf(w0, h, aP[i][j]);
                aC[i][j] = fmaf(w1v, h, aC[i][j]);
                aM[i][j] = fmaf(w2v, h, aM[i][j]);
              }
          }
      }
    }
    // plane e-1 complete after hidden e's kz=2 contribution
    if (e >= D0 + 1) {
      int d = e - 1;
#pragma unroll
      for (int i = 0; i < 2; ++i) {
        int gy = ty0 + py0 + i, gx = tx0 + px0;
        size_t v = (size_t)d * HW + gy * WW + gx;
        float2 pr;
        if (zeroPrev) { pr.x = 0.f; pr.y = 0.f; }
        else pr = *(const float2*)&prevBuf[v];
        float2 o;
        o.x = pr.x + coef * (pr.x - aM[i][0]);
        o.y = pr.y + coef * (pr.y - aM[i][1]);
        *(float2*)&outBuf[v] = o;
      }
    }
    // rotate ring (name rotation: no dynamic register indexing)
#pragma unroll
    for (int i = 0; i < 2; ++i)
#pragma unroll
      for (int j = 0; j < 2; ++j) {
        aM[i][j] = aC[i][j]; aC[i][j] = aP[i][j]; aP[i][j] = b2;
      }
    load_deriv(e + 2);  // overwrites slot comp_hidden(e) read (done pre-sync)
    __syncthreads();    // fences hbuf WAR + dbuf RAW for next iteration
  }
}

// ---------------------------------------------------------------------------
// Kernel C: t_next = fdiff_t(p,x) + fdiff_t(q,y) + fdiff_t(s,z) + zb
// ---------------------------------------------------------------------------
__global__ __launch_bounds__(256) void k_combine(
    const float* __restrict__ p, const float* __restrict__ q,
    const float* __restrict__ s_, const float* __restrict__ zb,
    float* __restrict__ tn) {
  int idx = blockIdx.x * 256 + threadIdx.x;
  int x = idx & (WW - 1);
  int y = (idx >> 8) & (HH - 1);
  int d = idx >> 16;
  float v = zb[idx];
  v += (x > 0 ? p[idx - 1] : 0.f) - (x < WW - 1 ? p[idx] : 0.f);
  v += (y > 0 ? q[idx - WW] : 0.f) - (y < HH - 1 ? q[idx] : 0.f);
  v += (d > 0 ? s_[idx - HW] : 0.f) - (d < DD - 1 ? s_[idx] : 0.f);
  tn[idx] = v;
}

// ---------------------------------------------------------------------------
extern "C" void kernel_launch(void* const* d_in, const int* in_sizes, int n_in,
                              void* d_out, int out_size, void* d_ws, size_t ws_size,
                              hipStream_t stream) {
  const float* image = (const float*)d_in[0];
  const float* sino  = (const float*)d_in[1];
  const float* W1    = (const float*)d_in[2];
  const float* B1    = (const float*)d_in[3];
  const float* W2    = (const float*)d_in[4];
  const float* B2    = (const float*)d_in[5];
  const float* ntx   = (const float*)d_in[6];
  const float* nty   = (const float*)d_in[7];
  const float* ntz   = (const float*)d_in[8];
  const float* nt    = (const float*)d_in[9];
  float* out = (float*)d_out;

  // workspace layout: corr(HW) | p | q | s | zb  -> 67.4 MB total
  float* corr = (float*)d_ws;
  float* p  = corr + HW;
  float* q  = p + NVOX;
  float* s_ = q + NVOX;
  float* zb = s_ + NVOX;

  // outs[0] = image
  hipMemcpyAsync(out, image, (size_t)NVOX * sizeof(float),
                 hipMemcpyDeviceToDevice, stream);

  for (int c = 0; c < 3; ++c) {
    const float* t = out + (size_t)c * NVOX;
    float* tn = out + (size_t)(c + 1) * NVOX;
    k_corr<<<HW / 256, 256, 0, stream>>>(t, sino, corr);
    // z: 4 basic-blocks x 2 depth chunks -> 512 blocks = 2 WG/CU
    k_blocks<<<dim3(WW / TS, HH / TS, 8), 256, 0, stream>>>(
        t, corr, p, q, s_, zb, W1, B1, W2, B2, ntx, nty, ntz, nt, c);
    k_combine<<<NVOX / 256, 256, 0, stream>>>(p, q, s_, zb, tn);
  }
}

// Round 5
// 975.571 us; speedup vs baseline: 6.1317x; 1.4120x over previous
//
#include <hip/hip_runtime.h>

#define DD 64
#define HH 256
#define WW 256
#define HW (HH * WW)      // 65536
#define NVOX (DD * HW)    // 4194304

#define TS 32             // output tile (H and W)
#define DR 36             // deriv region = TS+4 (row stride 36, even)
#define HR 34             // hidden region = TS+2
#define HP 34             // hbuf row stride (even -> float2-aligned)
#define CHB 22            // depth chunk: 3 chunks (22,22,20) -> grid z=12

// ---------------------------------------------------------------------------
// Kernel A: corr[h,w] = (sino[h,w] - sum_d t[d,h,w]) / DD
// ---------------------------------------------------------------------------
__global__ __launch_bounds__(256) void k_corr(const float* __restrict__ t,
                                              const float* __restrict__ sino,
                                              float* __restrict__ corr) {
  int idx = blockIdx.x * 256 + threadIdx.x;  // 0..HW-1
  float s = 0.f;
#pragma unroll 8
  for (int d = 0; d < DD; ++d) s += t[d * HW + idx];
  corr[idx] = (sino[idx] - s) * (1.0f / DD);
}

// ---------------------------------------------------------------------------
// Kernel B (R5): fused BasicBlock(b) on deriv_b(z), z = t + corr.
// R4 scatter structure (one hidden plane + register ring aM/aC/aP) plus:
//  - conv1 2x2-patch register blocking: 3x4x4 window via 24 ds_read_b64
//    (was 4x27 scalar b32) -> ~4x fewer conv1 LDS issues.
//  - HP 36->34, depth-split x3 -> LDS 52.5 KB, grid 768 = 3 WG/CU.
// ---------------------------------------------------------------------------
__global__ __launch_bounds__(256, 3) void k_blocks(
    const float* __restrict__ t, const float* __restrict__ corr,
    float* __restrict__ p, float* __restrict__ q, float* __restrict__ s_,
    float* __restrict__ zb,
    const float* __restrict__ W1g, const float* __restrict__ B1g,
    const float* __restrict__ W2g, const float* __restrict__ B2g,
    const float* __restrict__ ntx, const float* __restrict__ nty,
    const float* __restrict__ ntz, const float* __restrict__ nt, int c) {
  __shared__ __align__(16) float dbuf[3][DR][DR];   // 15.6 KB
  __shared__ __align__(16) float hbuf[8][HR][HP];   // 37.0 KB

  const int b = blockIdx.z & 3;
  const int D0 = (blockIdx.z >> 2) * CHB;           // 0, 22, 44
  const int Dend = (D0 + CHB < DD) ? (D0 + CHB) : DD;
  const int ty0 = blockIdx.y * TS;
  const int tx0 = blockIdx.x * TS;
  const int tid = threadIdx.x;

  const float* w1 = W1g + b * 216;  // [8][3][3][3]
  const float* w2 = W2g + b * 216;  // [8][3][3][3] (W2 shape (4,1,8,3,3,3))
  const float b2 = B2g[b];
  const float coef = (b == 0) ? ntx[c] : (b == 1) ? nty[c] : (b == 2) ? ntz[c] : nt[c];
  const float* prevBuf = (b == 0) ? p : (b == 1) ? q : (b == 2) ? s_ : t;
  float* outBuf = (b == 0) ? p : (b == 1) ? q : (b == 2) ? s_ : zb;
  const bool zeroPrev = (c == 0) && (b < 3);

  auto dslot = [](int f) { return (f + 6) % 3; };

  // ---- deriv plane f -> dbuf[dslot(f)]; out-of-range f writes zeros
  auto load_deriv = [&](int f) {
    int sl = dslot(f);
    for (int i = tid; i < DR * DR; i += 256) {
      int iy = i / DR, ix = i - iy * DR;
      int gy = ty0 - 2 + iy, gx = tx0 - 2 + ix;
      float v = 0.f;
      if (f >= 0 && f < DD && (unsigned)gy < HH && (unsigned)gx < WW) {
        int base = f * HW + gy * WW + gx;
        int cb = gy * WW + gx;
        if (b == 0) {
          if (gx + 1 < WW) v = t[base + 1] - t[base] + corr[cb + 1] - corr[cb];
        } else if (b == 1) {
          if (gy + 1 < HH) v = t[base + WW] - t[base] + corr[cb + WW] - corr[cb];
        } else if (b == 2) {
          if (f + 1 < DD) v = t[base + HW] - t[base];  // corr cancels along D
        } else {
          v = t[base] + corr[cb];
        }
      }
      dbuf[sl][iy][ix] = v;
    }
  };

  // ---- hidden plane e -> hbuf; 2x2 patch per thread, 17x17=289 patches.
  // Hidden exists only INSIDE the volume; conv2 SAME zero-pads it (R1 fix).
  auto comp_hidden = [&](int e) {
    const float* d0 = &dbuf[dslot(e - 1)][0][0];
    const float* d1 = &dbuf[dslot(e)][0][0];
    const float* d2 = &dbuf[dslot(e + 1)][0][0];
    for (int pi = tid; pi < 17 * 17; pi += 256) {
      int pr = pi / 17, pc = pi - pr * 17;
      int jy = pr * 2, jx = pc * 2;  // hidden patch origin (even -> aligned)
      float win[3][4][4];
#pragma unroll
      for (int r = 0; r < 4; ++r) {
        int off = (jy + r) * DR + jx;
        const float2* r0 = (const float2*)(d0 + off);
        const float2* r1 = (const float2*)(d1 + off);
        const float2* r2 = (const float2*)(d2 + off);
        float2 a, bb;
        a = r0[0]; bb = r0[1];
        win[0][r][0] = a.x; win[0][r][1] = a.y; win[0][r][2] = bb.x; win[0][r][3] = bb.y;
        a = r1[0]; bb = r1[1];
        win[1][r][0] = a.x; win[1][r][1] = a.y; win[1][r][2] = bb.x; win[1][r][3] = bb.y;
        a = r2[0]; bb = r2[1];
        win[2][r][0] = a.x; win[2][r][1] = a.y; win[2][r][2] = bb.x; win[2][r][3] = bb.y;
      }
      int gy0 = ty0 - 1 + jy, gx0 = tx0 - 1 + jx;
      bool in00 = ((unsigned)gy0 < HH) && ((unsigned)gx0 < WW);
      bool in01 = ((unsigned)gy0 < HH) && ((unsigned)(gx0 + 1) < WW);
      bool in10 = ((unsigned)(gy0 + 1) < HH) && ((unsigned)gx0 < WW);
      bool in11 = ((unsigned)(gy0 + 1) < HH) && ((unsigned)(gx0 + 1) < WW);
#pragma unroll 2
      for (int ch = 0; ch < 8; ++ch) {  // unroll 2: ILP w/o spill
        float bia = B1g[b * 8 + ch];
        float a00 = bia, a01 = bia, a10 = bia, a11 = bia;
        const float* wch = w1 + ch * 27;
#pragma unroll
        for (int kz = 0; kz < 3; ++kz)
#pragma unroll
          for (int ky = 0; ky < 3; ++ky)
#pragma unroll
            for (int kx = 0; kx < 3; ++kx) {
              float wv = wch[kz * 9 + ky * 3 + kx];
              a00 = fmaf(wv, win[kz][ky][kx], a00);
              a01 = fmaf(wv, win[kz][ky][kx + 1], a01);
              a10 = fmaf(wv, win[kz][ky + 1][kx], a10);
              a11 = fmaf(wv, win[kz][ky + 1][kx + 1], a11);
            }
        float2 r0, r1;
        r0.x = in00 ? fmaxf(a00, 0.f) : 0.f;
        r0.y = in01 ? fmaxf(a01, 0.f) : 0.f;
        r1.x = in10 ? fmaxf(a10, 0.f) : 0.f;
        r1.y = in11 ? fmaxf(a11, 0.f) : 0.f;
        *(float2*)&hbuf[ch][jy][jx] = r0;
        *(float2*)&hbuf[ch][jy + 1][jx] = r1;
      }
    }
  };

  const int txi = tid & 15, tyi = tid >> 4;
  const int px0 = txi * 2, py0 = tyi * 2;

  // register ring: aM = plane e-1, aC = plane e, aP = plane e+1
  float aM[2][2], aC[2][2], aP[2][2];
#pragma unroll
  for (int i = 0; i < 2; ++i)
#pragma unroll
    for (int j = 0; j < 2; ++j) { aM[i][j] = b2; aC[i][j] = b2; aP[i][j] = b2; }

  // prologue: deriv planes D0-2, D0-1, D0 (out-of-range -> zeros)
  load_deriv(D0 - 2);
  load_deriv(D0 - 1);
  load_deriv(D0);
  __syncthreads();

  for (int e = D0 - 1; e <= Dend; ++e) {
    const bool live = (e >= 0 && e < DD);
    if (live) comp_hidden(e);
    __syncthreads();
    if (live) {
      // scatter hidden e into aP(kz=0 -> e+1), aC(kz=1 -> e), aM(kz=2 -> e-1)
#pragma unroll 1
      for (int ch = 0; ch < 8; ++ch) {  // unroll 1: cap live set (R2 fix)
        float hwf[4][4];
#pragma unroll
        for (int r = 0; r < 4; ++r) {
          const float2* row = (const float2*)&hbuf[ch][py0 + r][px0];
          float2 a0 = row[0], a1 = row[1];
          hwf[r][0] = a0.x; hwf[r][1] = a0.y; hwf[r][2] = a1.x; hwf[r][3] = a1.y;
        }
        const float* wch = w2 + ch * 27;
#pragma unroll
        for (int ky = 0; ky < 3; ++ky)
#pragma unroll
          for (int kx = 0; kx < 3; ++kx) {
            float w0 = wch[0 + ky * 3 + kx];
            float w1v = wch[9 + ky * 3 + kx];
            float w2v = wch[18 + ky * 3 + kx];
#pragma unroll
            for (int i = 0; i < 2; ++i)
#pragma unroll
              for (int j = 0; j < 2; ++j) {
                float h = hwf[i + ky][j + kx];
                aP[i][j] = fmaf(w0, h, aP[i][j]);
                aC[i][j] = fmaf(w1v, h, aC[i][j]);
                aM[i][j] = fmaf(w2v, h, aM[i][j]);
              }
          }
      }
    }
    // plane e-1 complete after hidden e's kz=2 contribution
    if (e >= D0 + 1) {
      int d = e - 1;
#pragma unroll
      for (int i = 0; i < 2; ++i) {
        int gy = ty0 + py0 + i, gx = tx0 + px0;
        size_t v = (size_t)d * HW + gy * WW + gx;
        float2 pr;
        if (zeroPrev) { pr.x = 0.f; pr.y = 0.f; }
        else pr = *(const float2*)&prevBuf[v];
        float2 o;
        o.x = pr.x + coef * (pr.x - aM[i][0]);
        o.y = pr.y + coef * (pr.y - aM[i][1]);
        *(float2*)&outBuf[v] = o;
      }
    }
    // rotate ring (name rotation: no dynamic register indexing)
#pragma unroll
    for (int i = 0; i < 2; ++i)
#pragma unroll
      for (int j = 0; j < 2; ++j) {
        aM[i][j] = aC[i][j]; aC[i][j] = aP[i][j]; aP[i][j] = b2;
      }
    // safe: all threads passed the sync after comp_hidden(e), which read
    // the slot this overwrites ((e+2)%3 == (e-1)%3)
    load_deriv(e + 2);
    __syncthreads();    // fences hbuf WAR + dbuf RAW for next iteration
  }
}

// ---------------------------------------------------------------------------
// Kernel C: t_next = fdiff_t(p,x) + fdiff_t(q,y) + fdiff_t(s,z) + zb
// ---------------------------------------------------------------------------
__global__ __launch_bounds__(256) void k_combine(
    const float* __restrict__ p, const float* __restrict__ q,
    const float* __restrict__ s_, const float* __restrict__ zb,
    float* __restrict__ tn) {
  int idx = blockIdx.x * 256 + threadIdx.x;
  int x = idx & (WW - 1);
  int y = (idx >> 8) & (HH - 1);
  int d = idx >> 16;
  float v = zb[idx];
  v += (x > 0 ? p[idx - 1] : 0.f) - (x < WW - 1 ? p[idx] : 0.f);
  v += (y > 0 ? q[idx - WW] : 0.f) - (y < HH - 1 ? q[idx] : 0.f);
  v += (d > 0 ? s_[idx - HW] : 0.f) - (d < DD - 1 ? s_[idx] : 0.f);
  tn[idx] = v;
}

// ---------------------------------------------------------------------------
extern "C" void kernel_launch(void* const* d_in, const int* in_sizes, int n_in,
                              void* d_out, int out_size, void* d_ws, size_t ws_size,
                              hipStream_t stream) {
  const float* image = (const float*)d_in[0];
  const float* sino  = (const float*)d_in[1];
  const float* W1    = (const float*)d_in[2];
  const float* B1    = (const float*)d_in[3];
  const float* W2    = (const float*)d_in[4];
  const float* B2    = (const float*)d_in[5];
  const float* ntx   = (const float*)d_in[6];
  const float* nty   = (const float*)d_in[7];
  const float* ntz   = (const float*)d_in[8];
  const float* nt    = (const float*)d_in[9];
  float* out = (float*)d_out;

  // workspace layout: corr(HW) | p | q | s | zb  -> 67.4 MB total
  float* corr = (float*)d_ws;
  float* p  = corr + HW;
  float* q  = p + NVOX;
  float* s_ = q + NVOX;
  float* zb = s_ + NVOX;

  // outs[0] = image
  hipMemcpyAsync(out, image, (size_t)NVOX * sizeof(float),
                 hipMemcpyDeviceToDevice, stream);

  for (int c = 0; c < 3; ++c) {
    const float* t = out + (size_t)c * NVOX;
    float* tn = out + (size_t)(c + 1) * NVOX;
    k_corr<<<HW / 256, 256, 0, stream>>>(t, sino, corr);
    // z: 4 basic-blocks x 3 depth chunks -> 768 blocks = 3 WG/CU
    k_blocks<<<dim3(WW / TS, HH / TS, 12), 256, 0, stream>>>(
        t, corr, p, q, s_, zb, W1, B1, W2, B2, ntx, nty, ntz, nt, c);
    k_combine<<<NVOX / 256, 256, 0, stream>>>(p, q, s_, zb, tn);
  }
}

// Round 6
// 959.742 us; speedup vs baseline: 6.2328x; 1.0165x over previous
//
#include <hip/hip_runtime.h>

#define DD 64
#define HH 256
#define WW 256
#define HW (HH * WW)      // 65536
#define NVOX (DD * HW)    // 4194304

#define TS 32             // output tile (H and W)
#define DR 36             // deriv region = TS+4 (row stride 36, even)
#define HR 34             // hidden region = TS+2
#define HP 34             // hbuf row stride (even -> float2-aligned)
#define CHB 22            // depth chunk: 3 chunks (22,22,20) -> grid z=12
#define NPF 6             // prefetch slots = ceil(DR*DR/256)

// ---------------------------------------------------------------------------
// Kernel A: corr[h,w] = (sino[h,w] - sum_d t[d,h,w]) / DD
// ---------------------------------------------------------------------------
__global__ __launch_bounds__(256) void k_corr(const float* __restrict__ t,
                                              const float* __restrict__ sino,
                                              float* __restrict__ corr) {
  int idx = blockIdx.x * 256 + threadIdx.x;  // 0..HW-1
  float s = 0.f;
#pragma unroll 8
  for (int d = 0; d < DD; ++d) s += t[d * HW + idx];
  corr[idx] = (sino[idx] - s) * (1.0f / DD);
}

// ---------------------------------------------------------------------------
// Kernel B (R6): R5 scatter structure plus
//  - global->reg prefetch of the next deriv plane issued BEFORE conv1, LDS
//    write deferred to after the sync (hides L2/L3 latency; R5 exposed it
//    right before the barrier every plane-step).
//  - balanced conv1: phase1 = 256 patches (1/thread); phase2 = 33 leftover
//    patches as 132 (patch x ch-pair) tasks (R5: wave 0 did 2 full patches
//    while waves 1-3 did 1 -> 2x critical path at every barrier).
// ---------------------------------------------------------------------------
__global__ __launch_bounds__(256, 3) void k_blocks(
    const float* __restrict__ t, const float* __restrict__ corr,
    float* __restrict__ p, float* __restrict__ q, float* __restrict__ s_,
    float* __restrict__ zb,
    const float* __restrict__ W1g, const float* __restrict__ B1g,
    const float* __restrict__ W2g, const float* __restrict__ B2g,
    const float* __restrict__ ntx, const float* __restrict__ nty,
    const float* __restrict__ ntz, const float* __restrict__ nt, int c) {
  __shared__ __align__(16) float dbuf[3][DR][DR];   // 15.6 KB
  __shared__ __align__(16) float hbuf[8][HR][HP];   // 37.0 KB

  const int b = blockIdx.z & 3;
  const int D0 = (blockIdx.z >> 2) * CHB;           // 0, 22, 44
  const int Dend = (D0 + CHB < DD) ? (D0 + CHB) : DD;
  const int ty0 = blockIdx.y * TS;
  const int tx0 = blockIdx.x * TS;
  const int tid = threadIdx.x;

  const float* w1 = W1g + b * 216;  // [8][3][3][3]
  const float* w2 = W2g + b * 216;  // [8][3][3][3] (W2 shape (4,1,8,3,3,3))
  float b1[8];
#pragma unroll
  for (int ch = 0; ch < 8; ++ch) b1[ch] = B1g[b * 8 + ch];
  const float b2 = B2g[b];
  const float coef = (b == 0) ? ntx[c] : (b == 1) ? nty[c] : (b == 2) ? ntz[c] : nt[c];
  const float* prevBuf = (b == 0) ? p : (b == 1) ? q : (b == 2) ? s_ : t;
  float* outBuf = (b == 0) ? p : (b == 1) ? q : (b == 2) ? s_ : zb;
  const bool zeroPrev = (c == 0) && (b < 3);

  auto dslot = [](int f) { return (f + 6) % 3; };

  // ---- prefetch state: raw global values for deriv plane f
  float pA0[NPF], pA1[NPF], pC0[NPF], pC1[NPF];

  auto issue_loads = [&](int f) {
#pragma unroll
    for (int k = 0; k < NPF; ++k) {
      int i = tid + k * 256;
      pA0[k] = 0.f; pA1[k] = 0.f; pC0[k] = 0.f; pC1[k] = 0.f;
      if (i < DR * DR) {
        int iy = i / DR, ix = i - iy * DR;
        int gy = ty0 - 2 + iy, gx = tx0 - 2 + ix;
        if (f >= 0 && f < DD && (unsigned)gy < HH && (unsigned)gx < WW) {
          int base = f * HW + gy * WW + gx;
          int cb = gy * WW + gx;
          if (b == 0) {
            if (gx + 1 < WW) { pA0[k] = t[base]; pA1[k] = t[base + 1];
                               pC0[k] = corr[cb]; pC1[k] = corr[cb + 1]; }
          } else if (b == 1) {
            if (gy + 1 < HH) { pA0[k] = t[base]; pA1[k] = t[base + WW];
                               pC0[k] = corr[cb]; pC1[k] = corr[cb + WW]; }
          } else if (b == 2) {
            if (f + 1 < DD) { pA0[k] = t[base]; pA1[k] = t[base + HW]; }
          } else {
            pA0[k] = t[base]; pC0[k] = corr[cb];
          }
        }
      }
    }
  };
  auto write_deriv = [&](int f) {
    float* dst = &dbuf[dslot(f)][0][0];
#pragma unroll
    for (int k = 0; k < NPF; ++k) {
      int i = tid + k * 256;
      if (i < DR * DR) {
        float v;
        if (b == 3) v = pA0[k] + pC0[k];
        else v = (pA1[k] - pA0[k]) + (pC1[k] - pC0[k]);  // b=2: C terms are 0
        dst[i] = v;
      }
    }
  };

  // ---- conv1 for one 2x2 hidden patch at (jy,jx), channels [ch0,ch1)
  auto conv1_patch = [&](const float* d0, const float* d1, const float* d2,
                         int jy, int jx, int ch0, int ch1) {
    float win[3][4][4];
#pragma unroll
    for (int r = 0; r < 4; ++r) {
      int off = (jy + r) * DR + jx;
      const float2* r0 = (const float2*)(d0 + off);
      const float2* r1 = (const float2*)(d1 + off);
      const float2* r2 = (const float2*)(d2 + off);
      float2 a, bb;
      a = r0[0]; bb = r0[1];
      win[0][r][0] = a.x; win[0][r][1] = a.y; win[0][r][2] = bb.x; win[0][r][3] = bb.y;
      a = r1[0]; bb = r1[1];
      win[1][r][0] = a.x; win[1][r][1] = a.y; win[1][r][2] = bb.x; win[1][r][3] = bb.y;
      a = r2[0]; bb = r2[1];
      win[2][r][0] = a.x; win[2][r][1] = a.y; win[2][r][2] = bb.x; win[2][r][3] = bb.y;
    }
    int gy0 = ty0 - 1 + jy, gx0 = tx0 - 1 + jx;
    bool in00 = ((unsigned)gy0 < HH) && ((unsigned)gx0 < WW);
    bool in01 = ((unsigned)gy0 < HH) && ((unsigned)(gx0 + 1) < WW);
    bool in10 = ((unsigned)(gy0 + 1) < HH) && ((unsigned)gx0 < WW);
    bool in11 = ((unsigned)(gy0 + 1) < HH) && ((unsigned)(gx0 + 1) < WW);
#pragma unroll 2
    for (int ch = ch0; ch < ch1; ++ch) {
      float bia = b1[ch];
      float a00 = bia, a01 = bia, a10 = bia, a11 = bia;
      const float* wch = w1 + ch * 27;
#pragma unroll
      for (int kz = 0; kz < 3; ++kz)
#pragma unroll
        for (int ky = 0; ky < 3; ++ky)
#pragma unroll
          for (int kx = 0; kx < 3; ++kx) {
            float wv = wch[kz * 9 + ky * 3 + kx];
            a00 = fmaf(wv, win[kz][ky][kx], a00);
            a01 = fmaf(wv, win[kz][ky][kx + 1], a01);
            a10 = fmaf(wv, win[kz][ky + 1][kx], a10);
            a11 = fmaf(wv, win[kz][ky + 1][kx + 1], a11);
          }
      float2 r0v, r1v;
      r0v.x = in00 ? fmaxf(a00, 0.f) : 0.f;
      r0v.y = in01 ? fmaxf(a01, 0.f) : 0.f;
      r1v.x = in10 ? fmaxf(a10, 0.f) : 0.f;
      r1v.y = in11 ? fmaxf(a11, 0.f) : 0.f;
      *(float2*)&hbuf[ch][jy][jx] = r0v;
      *(float2*)&hbuf[ch][jy + 1][jx] = r1v;
    }
  };

  // ---- hidden plane e -> hbuf. Balanced: phase1 256 patches (1/thread),
  // phase2 = 33 leftover patches x 4 ch-pairs = 132 tasks (1/thread).
  auto comp_hidden = [&](int e) {
    const float* d0 = &dbuf[dslot(e - 1)][0][0];
    const float* d1 = &dbuf[dslot(e)][0][0];
    const float* d2 = &dbuf[dslot(e + 1)][0][0];
    {
      int prr = tid / 17, pcc = tid - prr * 17;     // patches 0..255
      conv1_patch(d0, d1, d2, prr * 2, pcc * 2, 0, 8);
    }
    if (tid < 132) {                                 // patches 256..288
      int m = tid >> 2, chp = (tid & 3) << 1;
      int pi = 256 + m;
      int prr = pi / 17, pcc = pi - prr * 17;
      conv1_patch(d0, d1, d2, prr * 2, pcc * 2, chp, chp + 2);
    }
  };

  const int txi = tid & 15, tyi = tid >> 4;
  const int px0 = txi * 2, py0 = tyi * 2;

  // register ring: aM = plane e-1, aC = plane e, aP = plane e+1
  float aM[2][2], aC[2][2], aP[2][2];
#pragma unroll
  for (int i = 0; i < 2; ++i)
#pragma unroll
    for (int j = 0; j < 2; ++j) { aM[i][j] = b2; aC[i][j] = b2; aP[i][j] = b2; }

  // prologue: deriv planes D0-2, D0-1, D0 (out-of-range -> zeros)
  issue_loads(D0 - 2); write_deriv(D0 - 2);
  issue_loads(D0 - 1); write_deriv(D0 - 1);
  issue_loads(D0);     write_deriv(D0);
  __syncthreads();

  for (int e = D0 - 1; e <= Dend; ++e) {
    const bool live = (e >= 0 && e < DD);
    // prefetch next deriv plane (global -> regs); overlaps conv1 compute
    issue_loads(e + 2);
    // prefetch prev-state operand for this iteration's output store
    float2 pr0, pr1;
    pr0.x = pr0.y = pr1.x = pr1.y = 0.f;
    const int d = e - 1;
    const bool doStore = (e >= D0 + 1);
    if (doStore && !zeroPrev) {
      size_t v0 = (size_t)d * HW + (size_t)(ty0 + py0) * WW + tx0 + px0;
      pr0 = *(const float2*)&prevBuf[v0];
      pr1 = *(const float2*)&prevBuf[v0 + WW];
    }
    if (live) comp_hidden(e);
    __syncthreads();  // hbuf RAW ready; all conv1 dbuf reads done
    if (live) {
      // scatter hidden e into aP(kz=0 -> e+1), aC(kz=1 -> e), aM(kz=2 -> e-1)
#pragma unroll 1
      for (int ch = 0; ch < 8; ++ch) {  // unroll 1: cap live set (R2 fix)
        float hwf[4][4];
#pragma unroll
        for (int r = 0; r < 4; ++r) {
          const float2* row = (const float2*)&hbuf[ch][py0 + r][px0];
          float2 a0 = row[0], a1 = row[1];
          hwf[r][0] = a0.x; hwf[r][1] = a0.y; hwf[r][2] = a1.x; hwf[r][3] = a1.y;
        }
        const float* wch = w2 + ch * 27;
#pragma unroll
        for (int ky = 0; ky < 3; ++ky)
#pragma unroll
          for (int kx = 0; kx < 3; ++kx) {
            float w0 = wch[0 + ky * 3 + kx];
            float w1v = wch[9 + ky * 3 + kx];
            float w2v = wch[18 + ky * 3 + kx];
#pragma unroll
            for (int i = 0; i < 2; ++i)
#pragma unroll
              for (int j = 0; j < 2; ++j) {
                float h = hwf[i + ky][j + kx];
                aP[i][j] = fmaf(w0, h, aP[i][j]);
                aC[i][j] = fmaf(w1v, h, aC[i][j]);
                aM[i][j] = fmaf(w2v, h, aM[i][j]);
              }
          }
      }
    }
    // deriv plane e+2 -> LDS (slot (e+2)%3 == (e-1)%3, freed by the sync)
    write_deriv(e + 2);
    // plane e-1 complete after hidden e's kz=2 contribution
    if (doStore) {
      size_t v0 = (size_t)d * HW + (size_t)(ty0 + py0) * WW + tx0 + px0;
      float2 o0, o1;
      o0.x = pr0.x + coef * (pr0.x - aM[0][0]);
      o0.y = pr0.y + coef * (pr0.y - aM[0][1]);
      o1.x = pr1.x + coef * (pr1.x - aM[1][0]);
      o1.y = pr1.y + coef * (pr1.y - aM[1][1]);
      *(float2*)&outBuf[v0] = o0;
      *(float2*)&outBuf[v0 + WW] = o1;
    }
    // rotate ring (name rotation: no dynamic register indexing)
#pragma unroll
    for (int i = 0; i < 2; ++i)
#pragma unroll
      for (int j = 0; j < 2; ++j) {
        aM[i][j] = aC[i][j]; aC[i][j] = aP[i][j]; aP[i][j] = b2;
      }
    __syncthreads();  // fences dbuf RAW + hbuf WAR for next iteration
  }
}

// ---------------------------------------------------------------------------
// Kernel C: t_next = fdiff_t(p,x) + fdiff_t(q,y) + fdiff_t(s,z) + zb
// ---------------------------------------------------------------------------
__global__ __launch_bounds__(256) void k_combine(
    const float* __restrict__ p, const float* __restrict__ q,
    const float* __restrict__ s_, const float* __restrict__ zb,
    float* __restrict__ tn) {
  int idx = blockIdx.x * 256 + threadIdx.x;
  int x = idx & (WW - 1);
  int y = (idx >> 8) & (HH - 1);
  int d = idx >> 16;
  float v = zb[idx];
  v += (x > 0 ? p[idx - 1] : 0.f) - (x < WW - 1 ? p[idx] : 0.f);
  v += (y > 0 ? q[idx - WW] : 0.f) - (y < HH - 1 ? q[idx] : 0.f);
  v += (d > 0 ? s_[idx - HW] : 0.f) - (d < DD - 1 ? s_[idx] : 0.f);
  tn[idx] = v;
}

// ---------------------------------------------------------------------------
extern "C" void kernel_launch(void* const* d_in, const int* in_sizes, int n_in,
                              void* d_out, int out_size, void* d_ws, size_t ws_size,
                              hipStream_t stream) {
  const float* image = (const float*)d_in[0];
  const float* sino  = (const float*)d_in[1];
  const float* W1    = (const float*)d_in[2];
  const float* B1    = (const float*)d_in[3];
  const float* W2    = (const float*)d_in[4];
  const float* B2    = (const float*)d_in[5];
  const float* ntx   = (const float*)d_in[6];
  const float* nty   = (const float*)d_in[7];
  const float* ntz   = (const float*)d_in[8];
  const float* nt    = (const float*)d_in[9];
  float* out = (float*)d_out;

  // workspace layout: corr(HW) | p | q | s | zb  -> 67.4 MB total
  float* corr = (float*)d_ws;
  float* p  = corr + HW;
  float* q  = p + NVOX;
  float* s_ = q + NVOX;
  float* zb = s_ + NVOX;

  // outs[0] = image
  hipMemcpyAsync(out, image, (size_t)NVOX * sizeof(float),
                 hipMemcpyDeviceToDevice, stream);

  for (int c = 0; c < 3; ++c) {
    const float* t = out + (size_t)c * NVOX;
    float* tn = out + (size_t)(c + 1) * NVOX;
    k_corr<<<HW / 256, 256, 0, stream>>>(t, sino, corr);
    // z: 4 basic-blocks x 3 depth chunks -> 768 blocks = 3 WG/CU
    k_blocks<<<dim3(WW / TS, HH / TS, 12), 256, 0, stream>>>(
        t, corr, p, q, s_, zb, W1, B1, W2, B2, ntx, nty, ntz, nt, c);
    k_combine<<<NVOX / 256, 256, 0, stream>>>(p, q, s_, zb, tn);
  }
}